// Round 4
// 803.719 us; speedup vs baseline: 1.0134x; 1.0134x over previous
//
#include <hip/hip_runtime.h>
#include <hip/hip_bf16.h>
#include <math.h>

// ---------------------------------------------------------------------------
// CrossAttentionQuerySelector fused kernel (MI355X / gfx950)
//
// R4 CONTROL: round-0 source VERBATIM (the last harness-verified passing
// kernel, 814 us). R1/R2/R3 all failed; the only variable common to all
// three failures and absent here is the min-waves __launch_bounds__ hint.
// This run discriminates {hint miscompiles} vs {bench environment drift}.
// ---------------------------------------------------------------------------

typedef float  f32x4  __attribute__((ext_vector_type(4)));
typedef __bf16 bf16x8 __attribute__((ext_vector_type(8)));
typedef __bf16 bf16x4 __attribute__((ext_vector_type(4)));

// workspace layout (bytes)
#define OFF_QKW   0         // 32x256 bf16 (rows 24..31 zero)
#define OFF_WV    16384     // 256x256 bf16
#define OFF_OUTW  147456    // 256x256 bf16
#define OFF_W1    278528    // 512x256 bf16
#define OFF_W2    540672    // 256x512 bf16
#define OFF_QS    802816    // 3x256 f32 (scaled q projections)

// LDS layout (bytes)
#define SA        528       // row stride for 264-bf16 rows (16B aligned, 2-way banks)
#define SCORES_B  33792     // 64 rows x 32 f32 (stride 128 B)
#define CTX_B     41984     // 32 rows x SA (ctx, then q)
#define HMID_S    1040      // hmid row stride (520 bf16), lives at base 0
#define FIN_S     1024      // final f32 row stride, lives at base 0
#define SMEM_BYTES 58880

__global__ void prep_qs_k(const float* __restrict__ slot, const float* __restrict__ ipw,
                          const float* __restrict__ ipb, float* __restrict__ qs) {
  // 768 threads: (s,d) pairs. qs[s*256+d] = (slot[s]·wq[d] + bq[d]) / sqrt(32)
  const int tid = threadIdx.x;
  const int d = tid & 255, s = tid >> 8;
  const float* wr = ipw + d * 256;
  const float* sr = slot + s * 256;
  float acc = ipb[d];
  for (int i = 0; i < 256; ++i) acc += sr[i] * wr[i];
  qs[s * 256 + d] = acc * 0.17677669529663687f;
}

__global__ void prep_qkw_k(const float* __restrict__ ipw, const float* __restrict__ qs,
                           __bf16* __restrict__ qkw) {
  // qk_w[j = h*3+s][i] = sum_hd qs[s][h*32+hd] * wk[h*32+hd][i]; rows 24..31 = 0
  const int j = blockIdx.x, i = threadIdx.x;
  float v = 0.f;
  if (j < 24) {
    const int h = j / 3, s = j - h * 3;
    for (int hd = 0; hd < 32; ++hd)
      v += qs[s * 256 + h * 32 + hd] * ipw[(256 + h * 32 + hd) * 256 + i];
  }
  qkw[j * 256 + i] = (__bf16)v;
}

__global__ void prep_cvt_k(const float* __restrict__ ipw, const float* __restrict__ outw_f,
                           const float* __restrict__ w1f, const float* __restrict__ w2f,
                           __bf16* __restrict__ wvb, __bf16* __restrict__ outwb,
                           __bf16* __restrict__ w1b, __bf16* __restrict__ w2b) {
  for (int idx = blockIdx.x * blockDim.x + threadIdx.x; idx < 393216;
       idx += gridDim.x * blockDim.x) {
    if (idx < 65536)        wvb[idx]            = (__bf16)ipw[131072 + idx];   // wv rows 512..767
    else if (idx < 131072)  outwb[idx - 65536]  = (__bf16)outw_f[idx - 65536];
    else if (idx < 262144)  w1b[idx - 131072]   = (__bf16)w1f[idx - 131072];
    else                    w2b[idx - 262144]   = (__bf16)w2f[idx - 262144];
  }
}

__global__ void __launch_bounds__(512) ca_main_k(
    const float* __restrict__ c0, const float* __restrict__ c1, const float* __restrict__ c2,
    const float* __restrict__ c3, const float* __restrict__ c4, const float* __restrict__ c5,
    const float* __restrict__ c6,
    const float* __restrict__ slotq, const float* __restrict__ ipb,
    const float* __restrict__ outb, const float* __restrict__ ln1g, const float* __restrict__ ln1b,
    const float* __restrict__ b1v, const float* __restrict__ b2v,
    const float* __restrict__ ln2g, const float* __restrict__ ln2b,
    const __bf16* __restrict__ qkw, const __bf16* __restrict__ wv,
    const __bf16* __restrict__ outw, const __bf16* __restrict__ w1b,
    const __bf16* __restrict__ w2b, float* __restrict__ out) {
  __shared__ __align__(16) unsigned char sm[SMEM_BYTES];
  const int tid   = threadIdx.x;
  const int wv_id = tid >> 6;   // wave 0..7
  const int lane  = tid & 63;
  const int l15   = lane & 15;
  const int quad  = lane >> 4;
  const long n0   = (long)blockIdx.x * 8;
  const f32x4 fzero = {0.f, 0.f, 0.f, 0.f};

  // ---- Phase 0: stage kv (8 tok x 7 cand x 256) as bf16, rows r=t*7+k ----
  {
    const float* cs[7] = {c0, c1, c2, c3, c4, c5, c6};
    const int t = tid >> 6;      // token 0..7 (one wave per token)
    const int q4 = tid & 63;     // 4-float chunk
#pragma unroll
    for (int k = 0; k < 7; ++k) {
      f32x4 v = *(const f32x4*)(cs[k] + (n0 + t) * 256 + q4 * 4);
      bf16x4 hv;
      hv[0] = (__bf16)v[0]; hv[1] = (__bf16)v[1];
      hv[2] = (__bf16)v[2]; hv[3] = (__bf16)v[3];
      *(bf16x4*)(sm + (t * 7 + k) * SA + q4 * 8) = hv;
    }
    bf16x4 z; z[0] = z[1] = z[2] = z[3] = (__bf16)0.f;
    *(bf16x4*)(sm + (56 + t) * SA + q4 * 8) = z;   // zero pad rows 56..63
  }
  __syncthreads();

  // ---- Phase 1: scores = kv @ qk_w^T -> LDS f32 [64 x 32] ----
  {
    const int mt = wv_id >> 1, nt = wv_id & 1;
    f32x4 acc = fzero;
    const int arow = mt * 16 + l15;
    const int brow = nt * 16 + l15;
#pragma unroll
    for (int ks = 0; ks < 8; ++ks) {
      const int k0 = ks * 32 + quad * 8;
      bf16x8 a = *(const bf16x8*)(sm + arow * SA + k0 * 2);
      bf16x8 b = *(const bf16x8*)(qkw + brow * 256 + k0);
      acc = __builtin_amdgcn_mfma_f32_16x16x32_bf16(a, b, acc, 0, 0, 0);
    }
#pragma unroll
    for (int r = 0; r < 4; ++r) {
      const int row = mt * 16 + quad * 4 + r;
      *(float*)(sm + SCORES_B + row * 128 + (nt * 16 + l15) * 4) = acc[r];
    }
  }

  // ---- Phase 2: vh = kv @ wv^T (accumulators stay in registers) ----
  f32x4 vacc[4][2];
#pragma unroll
  for (int m = 0; m < 4; ++m)
#pragma unroll
    for (int n = 0; n < 2; ++n) vacc[m][n] = fzero;
  {
#pragma unroll
    for (int ks = 0; ks < 8; ++ks) {
      const int k0 = ks * 32 + quad * 8;
      bf16x8 bb[2];
#pragma unroll
      for (int n = 0; n < 2; ++n) {
        const int brow = (wv_id * 2 + n) * 16 + l15;
        bb[n] = *(const bf16x8*)(wv + brow * 256 + k0);
      }
#pragma unroll
      for (int m = 0; m < 4; ++m) {
        bf16x8 a = *(const bf16x8*)(sm + (m * 16 + l15) * SA + k0 * 2);
#pragma unroll
        for (int n = 0; n < 2; ++n)
          vacc[m][n] = __builtin_amdgcn_mfma_f32_16x16x32_bf16(a, bb[n], vacc[m][n], 0, 0, 0);
      }
    }
  }
  __syncthreads();   // all kv reads + score writes complete

  // ---- Phase 3a: softmax over k (192 groups: 8 tok x 24 (h,s)) ----
  if (tid < 192) {
    const int t = tid / 24, j = tid - t * 24;
    float* sp = (float*)(sm + SCORES_B);
    float v[7]; float mx = -1e30f;
#pragma unroll
    for (int k = 0; k < 7; ++k) { v[k] = sp[(t * 7 + k) * 32 + j]; mx = fmaxf(mx, v[k]); }
    float ssum = 0.f;
#pragma unroll
    for (int k = 0; k < 7; ++k) { v[k] = __expf(v[k] - mx); ssum += v[k]; }
    const float inv = 1.f / ssum;
#pragma unroll
    for (int k = 0; k < 7; ++k) sp[(t * 7 + k) * 32 + j] = v[k] * inv;
  }
  // ---- Phase 3b: write vh (+bv) over the kv region ----
  {
#pragma unroll
    for (int n = 0; n < 2; ++n) {
      const int col = (wv_id * 2 + n) * 16 + l15;
      const float bvc = ipb[512 + col];
#pragma unroll
      for (int m = 0; m < 4; ++m)
#pragma unroll
        for (int r = 0; r < 4; ++r) {
          const int row = m * 16 + quad * 4 + r;
          *(__bf16*)(sm + row * SA + col * 2) = (__bf16)(vacc[m][n][r] + bvc);
        }
    }
  }
  __syncthreads();

  // ---- Phase 4: ctx[t,s,d] = sum_k attn[t,h(d),s,k] * vh[t,k,d] ----
  {
    const int d = tid & 255;
    const int hh = d >> 5;
    const int half = tid >> 8;
    const float* ap = (const float*)(sm + SCORES_B);
#pragma unroll
    for (int tt = 0; tt < 4; ++tt) {
      const int t = half * 4 + tt;
      float vvv[7];
#pragma unroll
      for (int k = 0; k < 7; ++k)
        vvv[k] = (float)*(const __bf16*)(sm + (t * 7 + k) * SA + d * 2);
#pragma unroll
      for (int s = 0; s < 3; ++s) {
        float c = 0.f;
#pragma unroll
        for (int k = 0; k < 7; ++k) c += ap[(t * 7 + k) * 32 + hh * 3 + s] * vvv[k];
        *(__bf16*)(sm + CTX_B + (t * 3 + s) * SA + d * 2) = (__bf16)c;
      }
    }
#pragma unroll
    for (int it = 0; it < 4; ++it) {   // zero ctx pad rows 24..31
      const int idx = tid + it * 512;
      const int r = 24 + (idx >> 8);
      const int dd = idx & 255;
      *(__bf16*)(sm + CTX_B + r * SA + dd * 2) = (__bf16)0.f;
    }
  }
  __syncthreads();

  // ---- Phase 5: attn_out = ctx @ out_w^T ----
  f32x4 oacc[2][2];
#pragma unroll
  for (int m = 0; m < 2; ++m)
#pragma unroll
    for (int n = 0; n < 2; ++n) oacc[m][n] = fzero;
  {
#pragma unroll
    for (int ks = 0; ks < 8; ++ks) {
      const int k0 = ks * 32 + quad * 8;
      bf16x8 bb[2];
#pragma unroll
      for (int n = 0; n < 2; ++n) {
        const int brow = (wv_id * 2 + n) * 16 + l15;
        bb[n] = *(const bf16x8*)(outw + brow * 256 + k0);
      }
#pragma unroll
      for (int m = 0; m < 2; ++m) {
        bf16x8 a = *(const bf16x8*)(sm + CTX_B + (m * 16 + l15) * SA + k0 * 2);
#pragma unroll
        for (int n = 0; n < 2; ++n)
          oacc[m][n] = __builtin_amdgcn_mfma_f32_16x16x32_bf16(a, bb[n], oacc[m][n], 0, 0, 0);
      }
    }
  }
  __syncthreads();   // all ctx reads done; safe to overwrite with q
  {
#pragma unroll
    for (int n = 0; n < 2; ++n) {
      const int col = (wv_id * 2 + n) * 16 + l15;
      const float ob = outb[col];
#pragma unroll
      for (int m = 0; m < 2; ++m)
#pragma unroll
        for (int r = 0; r < 4; ++r) {
          const int row = m * 16 + quad * 4 + r;
          const int s = row % 3;
          const float val = oacc[m][n][r] + ob + slotq[s * 256 + col];
          *(__bf16*)(sm + CTX_B + row * SA + col * 2) = (__bf16)val;
        }
    }
  }
  __syncthreads();

  // ---- Phase 6: LN1 in place (rows 0..23) -> q ----
  {
#pragma unroll
    for (int rr = 0; rr < 3; ++rr) {
      const int row = wv_id * 3 + rr;
      __bf16* p = (__bf16*)(sm + CTX_B + row * SA);
      bf16x4 xv = *(const bf16x4*)(p + lane * 4);
      const float x0 = (float)xv[0], x1 = (float)xv[1], x2 = (float)xv[2], x3 = (float)xv[3];
      float s1 = x0 + x1 + x2 + x3;
      float s2 = x0 * x0 + x1 * x1 + x2 * x2 + x3 * x3;
#pragma unroll
      for (int msk = 1; msk < 64; msk <<= 1) {
        s1 += __shfl_xor(s1, msk, 64);
        s2 += __shfl_xor(s2, msk, 64);
      }
      const float mean = s1 * 0.00390625f;
      float var = s2 * 0.00390625f - mean * mean;
      var = fmaxf(var, 0.f);
      const float rstd = rsqrtf(var + 1e-5f);
      f32x4 g = *(const f32x4*)(ln1g + lane * 4);
      f32x4 b = *(const f32x4*)(ln1b + lane * 4);
      bf16x4 y;
      y[0] = (__bf16)((x0 - mean) * rstd * g[0] + b[0]);
      y[1] = (__bf16)((x1 - mean) * rstd * g[1] + b[1]);
      y[2] = (__bf16)((x2 - mean) * rstd * g[2] + b[2]);
      y[3] = (__bf16)((x3 - mean) * rstd * g[3] + b[3]);
      *(bf16x4*)(p + lane * 4) = y;
    }
  }
  __syncthreads();

  // ---- Phase 7: mlp1 = gelu(q @ w1^T + b1) -> hmid (base 0, stride 1040) ----
  {
    f32x4 macc[2][4];
#pragma unroll
    for (int m = 0; m < 2; ++m)
#pragma unroll
      for (int n = 0; n < 4; ++n) macc[m][n] = fzero;
#pragma unroll
    for (int ks = 0; ks < 8; ++ks) {
      const int k0 = ks * 32 + quad * 8;
      bf16x8 a[2];
#pragma unroll
      for (int m = 0; m < 2; ++m)
        a[m] = *(const bf16x8*)(sm + CTX_B + (m * 16 + l15) * SA + k0 * 2);
#pragma unroll
      for (int n = 0; n < 4; ++n) {
        const int brow = (wv_id * 4 + n) * 16 + l15;
        bf16x8 b = *(const bf16x8*)(w1b + brow * 256 + k0);
#pragma unroll
        for (int m = 0; m < 2; ++m)
          macc[m][n] = __builtin_amdgcn_mfma_f32_16x16x32_bf16(a[m], b, macc[m][n], 0, 0, 0);
      }
    }
#pragma unroll
    for (int n = 0; n < 4; ++n) {
      const int col = (wv_id * 4 + n) * 16 + l15;
      const float bc = b1v[col];
#pragma unroll
      for (int m = 0; m < 2; ++m)
#pragma unroll
        for (int r = 0; r < 4; ++r) {
          const int row = m * 16 + quad * 4 + r;
          const float x = macc[m][n][r] + bc;
          const float ge = 0.5f * x * (1.f + erff(x * 0.70710678118654752f));
          *(__bf16*)(sm + row * HMID_S + col * 2) = (__bf16)ge;
        }
    }
  }
  __syncthreads();

  // ---- Phase 8: mlp2 = hmid @ w2^T ----
  f32x4 facc[2][2];
#pragma unroll
  for (int m = 0; m < 2; ++m)
#pragma unroll
    for (int n = 0; n < 2; ++n) facc[m][n] = fzero;
  {
#pragma unroll
    for (int ks = 0; ks < 16; ++ks) {
      const int k0 = ks * 32 + quad * 8;
      bf16x8 a[2];
#pragma unroll
      for (int m = 0; m < 2; ++m)
        a[m] = *(const bf16x8*)(sm + (m * 16 + l15) * HMID_S + k0 * 2);
#pragma unroll
      for (int n = 0; n < 2; ++n) {
        const int brow = (wv_id * 2 + n) * 16 + l15;
        bf16x8 b = *(const bf16x8*)(w2b + brow * 512 + k0);
#pragma unroll
        for (int m = 0; m < 2; ++m)
          facc[m][n] = __builtin_amdgcn_mfma_f32_16x16x32_bf16(a[m], b, facc[m][n], 0, 0, 0);
      }
    }
  }
  __syncthreads();   // all hmid reads done; safe to overwrite with final f32
  {
#pragma unroll
    for (int n = 0; n < 2; ++n) {
      const int col = (wv_id * 2 + n) * 16 + l15;
      const float bc = b2v[col];
#pragma unroll
      for (int m = 0; m < 2; ++m)
#pragma unroll
        for (int r = 0; r < 4; ++r) {
          const int row = m * 16 + quad * 4 + r;
          const float qv = (float)*(const __bf16*)(sm + CTX_B + row * SA + col * 2);
          *(float*)(sm + row * FIN_S + col * 4) = facc[m][n][r] + bc + qv;
        }
    }
  }
  __syncthreads();

  // ---- Phase 9: LN2 + coalesced fp32 output ----
  {
#pragma unroll
    for (int rr = 0; rr < 3; ++rr) {
      const int row = wv_id * 3 + rr;   // 0..23 = t*3+s
      f32x4 x = *(const f32x4*)(sm + row * FIN_S + lane * 16);
      float s1 = x[0] + x[1] + x[2] + x[3];
      float s2 = x[0] * x[0] + x[1] * x[1] + x[2] * x[2] + x[3] * x[3];
#pragma unroll
      for (int msk = 1; msk < 64; msk <<= 1) {
        s1 += __shfl_xor(s1, msk, 64);
        s2 += __shfl_xor(s2, msk, 64);
      }
      const float mean = s1 * 0.00390625f;
      float var = s2 * 0.00390625f - mean * mean;
      var = fmaxf(var, 0.f);
      const float rstd = rsqrtf(var + 1e-5f);
      f32x4 g = *(const f32x4*)(ln2g + lane * 4);
      f32x4 b = *(const f32x4*)(ln2b + lane * 4);
      f32x4 y;
      y[0] = (x[0] - mean) * rstd * g[0] + b[0];
      y[1] = (x[1] - mean) * rstd * g[1] + b[1];
      y[2] = (x[2] - mean) * rstd * g[2] + b[2];
      y[3] = (x[3] - mean) * rstd * g[3] + b[3];
      const int t = row / 3, s = row - (row / 3) * 3;
      *(f32x4*)(out + ((n0 + t) * 3 + s) * 256 + lane * 4) = y;
    }
  }
}

extern "C" void kernel_launch(void* const* d_in, const int* in_sizes, int n_in,
                              void* d_out, int out_size, void* d_ws, size_t ws_size,
                              hipStream_t stream) {
  const float* c0 = (const float*)d_in[0];
  const float* c1 = (const float*)d_in[1];
  const float* c2 = (const float*)d_in[2];
  const float* c3 = (const float*)d_in[3];
  const float* c4 = (const float*)d_in[4];
  const float* c5 = (const float*)d_in[5];
  const float* c6 = (const float*)d_in[6];
  const float* slotq  = (const float*)d_in[7];
  const float* ipw    = (const float*)d_in[8];
  const float* ipb    = (const float*)d_in[9];
  const float* outw_f = (const float*)d_in[10];
  const float* outb   = (const float*)d_in[11];
  const float* ln1g   = (const float*)d_in[12];
  const float* ln1b   = (const float*)d_in[13];
  const float* w1f    = (const float*)d_in[14];
  const float* b1v    = (const float*)d_in[15];
  const float* w2f    = (const float*)d_in[16];
  const float* b2v    = (const float*)d_in[17];
  const float* ln2g   = (const float*)d_in[18];
  const float* ln2b   = (const float*)d_in[19];

  char* ws = (char*)d_ws;
  __bf16* qkw   = (__bf16*)(ws + OFF_QKW);
  __bf16* wvb   = (__bf16*)(ws + OFF_WV);
  __bf16* outwb = (__bf16*)(ws + OFF_OUTW);
  __bf16* w1bb  = (__bf16*)(ws + OFF_W1);
  __bf16* w2bb  = (__bf16*)(ws + OFF_W2);
  float*  qs    = (float*)(ws + OFF_QS);

  hipLaunchKernelGGL(prep_qs_k, dim3(1), dim3(768), 0, stream, slotq, ipw, ipb, qs);
  hipLaunchKernelGGL(prep_cvt_k, dim3(384), dim3(512), 0, stream,
                     ipw, outw_f, w1f, w2f, wvb, outwb, w1bb, w2bb);
  hipLaunchKernelGGL(prep_qkw_k, dim3(32), dim3(256), 0, stream, ipw, qs, qkw);
  hipLaunchKernelGGL(ca_main_k, dim3(4096), dim3(512), 0, stream,
                     c0, c1, c2, c3, c4, c5, c6, slotq, ipb, outb, ln1g, ln1b,
                     b1v, b2v, ln2g, ln2b, qkw, wvb, outwb, w1bb, w2bb,
                     (float*)d_out);
}